// Round 3
// baseline (316.199 us; speedup 1.0000x reference)
//
#include <hip/hip_runtime.h>
#include <math.h>

#define TPB 256

__device__ __forceinline__ float2 cmul(float2 a, float2 b) {
    return make_float2(a.x * b.x - a.y * b.y, a.x * b.y + a.y * b.x);
}

// XOR swizzle on the complex (float2) index: every access phase in this kernel
// hits each bank-pair exactly 4x per wave64 b64 access = the 4-round minimum.
__device__ __forceinline__ int sw2(int i) { return i ^ ((i >> 4) & 15); }

__device__ __forceinline__ void dft4(float2& a, float2& b, float2& c, float2& d) {
    float2 t0 = make_float2(a.x + c.x, a.y + c.y);
    float2 t1 = make_float2(a.x - c.x, a.y - c.y);
    float2 t2 = make_float2(b.x + d.x, b.y + d.y);
    float2 t3 = make_float2(b.x - d.x, b.y - d.y);
    a = make_float2(t0.x + t2.x, t0.y + t2.y);
    b = make_float2(t1.x + t3.y, t1.y - t3.x);   // t1 - i*t3
    c = make_float2(t0.x - t2.x, t0.y - t2.y);
    d = make_float2(t1.x - t3.y, t1.y + t3.x);   // t1 + i*t3
}

// In-register 16-point DFT. Input v[l]; output y[m] lands at v[4*(m&3) + (m>>2)].
__device__ __forceinline__ void dft16(float2 v[16]) {
#pragma unroll
    for (int j = 0; j < 4; ++j) dft4(v[j], v[4 + j], v[8 + j], v[12 + j]);
    const float C1 = 0.9238795325112867f, S1 = 0.3826834323650898f;
    const float R2 = 0.7071067811865476f;
    v[5]  = cmul(v[5],  make_float2( C1, -S1));   // w16^1
    v[9]  = cmul(v[9],  make_float2( R2, -R2));   // w16^2
    v[13] = cmul(v[13], make_float2( S1, -C1));   // w16^3
    v[6]  = cmul(v[6],  make_float2( R2, -R2));   // w16^2
    v[10] = cmul(v[10], make_float2(0.f, -1.f));  // w16^4
    v[14] = cmul(v[14], make_float2(-R2, -R2));   // w16^6
    v[7]  = cmul(v[7],  make_float2( S1, -C1));   // w16^3
    v[11] = cmul(v[11], make_float2(-R2, -R2));   // w16^6
    v[15] = cmul(v[15], make_float2(-C1,  S1));   // w16^9
#pragma unroll
    for (int b = 0; b < 4; ++b) dft4(v[4 * b], v[4 * b + 1], v[4 * b + 2], v[4 * b + 3]);
}

__global__ __launch_bounds__(TPB, 5) void snr_kernel(const float* __restrict__ x,
                                                     const float* __restrict__ targets,
                                                     float* __restrict__ out) {
    __shared__ __align__(16) float2 Z[4096];   // 32768 B exactly -> 5 blocks/CU
    float* zf = (float*)Z;                     // overlay: spec at [0..5], red at [8..11]

    const int t = threadIdx.x;
    const int blk = blockIdx.x;

    // ---- every thread computes r (uniform; avoids LDS broadcast + barrier) ----
    int r;
    {
        float tg = targets[blk];
        const float df = 0.00244140625f;  // 10/4096 exact; f[i] = i*df exact in fp32
        int c0 = (int)(tg * 409.6f) - 2;
        if (c0 < 0) c0 = 0;
        r = c0;
        float best = fabsf(df * (float)c0 - tg);
        for (int i = c0 + 1; i <= c0 + 4 && i <= 4096; ++i) {
            float dd = fabsf(df * (float)i - tg);
            if (dd < best) { best = dd; r = i; }  // strict <: first-min wins == argmin
        }
    }

    // ---- Load: thread t owns c[t + 256*l] (8B/lane, 512B contiguous per wave) ----
    float2 v[16];
    const float2* row = (const float2*)(x + (size_t)blk * 8192);
#pragma unroll
    for (int l = 0; l < 16; ++l) v[l] = row[t + 256 * l];

    // ======== stage 0: s=1, n=4096, p=t; writes idx=16t+m ========
    dft16(v);
    {
        float ang = -1.5339807878856412e-3f * (float)t;  // -2pi/4096 * t
        float sn, cs; __sincosf(ang, &sn, &cs);
        float2 w1 = make_float2(cs, sn);
        float2 w2 = cmul(w1, w1), w3 = cmul(w2, w1);
        float2 w4 = cmul(w2, w2), w8 = cmul(w4, w4), w12 = cmul(w8, w4);
        float2 wa[4] = {make_float2(1.f, 0.f), w1, w2, w3};
        float2 wb[4] = {make_float2(1.f, 0.f), w4, w8, w12};
#pragma unroll
        for (int m = 0; m < 16; ++m) {
            Z[sw2(16 * t + m)] = cmul(v[4 * (m & 3) + (m >> 2)], cmul(wb[m >> 2], wa[m & 3]));
        }
    }
    __syncthreads();

    // ======== stage 1: s=16, n=256, p=t>>4, q=t&15 ========
#pragma unroll
    for (int l = 0; l < 16; ++l) v[l] = Z[sw2(t + 256 * l)];
    __syncthreads();   // in-place exchange: all reads before any writes
    dft16(v);
    {
        const int p = t >> 4, q = t & 15;
        float ang = -0.02454369260617026f * (float)p;  // -2pi/256 * p
        float sn, cs; __sincosf(ang, &sn, &cs);
        float2 w1 = make_float2(cs, sn);
        float2 w2 = cmul(w1, w1), w3 = cmul(w2, w1);
        float2 w4 = cmul(w2, w2), w8 = cmul(w4, w4), w12 = cmul(w8, w4);
        float2 wa[4] = {make_float2(1.f, 0.f), w1, w2, w3};
        float2 wb[4] = {make_float2(1.f, 0.f), w4, w8, w12};
#pragma unroll
        for (int m = 0; m < 16; ++m) {
            Z[sw2(q + 256 * p + 16 * m)] = cmul(v[4 * (m & 3) + (m >> 2)], cmul(wb[m >> 2], wa[m & 3]));
        }
    }
    __syncthreads();

    // ======== stage 2 (fused with rfft split): read column t AND column 256-t ========
    // Stage-2 DFT on column c's inputs yields Z[c + 256m] with no stage twiddle.
    float2 va[16], vb[16];
    const int tp = (256 - t) & 255;
#pragma unroll
    for (int l = 0; l < 16; ++l) va[l] = Z[sw2(t + 256 * l)];
#pragma unroll
    for (int l = 0; l < 16; ++l) vb[l] = Z[sw2(tp + 256 * l)];
    __syncthreads();   // Z free after this: spec/red overlay OK
    dft16(va);         // Z[t  + 256m] = va[4*(m&3)+(m>>2)]
    dft16(vb);         // Z[tp + 256m] = vb[4*(m&3)+(m>>2)]

    // ---- rfft split + on-the-fly band sum & special-bin capture ----
    // Zn = Z[(4096-k)&4095] for k=t+256m lives at column tp, index m' (below).
    const int r2 = 2 * r;
    float band = 0.f;
    {
        float ang = -7.669903939428206e-4f * (float)t;  // -pi/4096 * t
        float sn, cs; __sincosf(ang, &sn, &cs);
        float2 wk = make_float2(cs, sn);
        const float2 wstep = make_float2(0.9807852804032304f, -0.19509032201612825f);  // e^{-i pi/16}
#pragma unroll
        for (int m = 0; m < 16; ++m) {
            int k = t + 256 * m;
            float2 Zk = va[4 * (m & 3) + (m >> 2)];
            int mp = (t == 0) ? ((16 - m) & 15) : (15 - m);
            float2 Zn = vb[4 * (mp & 3) + (mp >> 2)];
            float sx = Zk.x + Zn.x, sy = Zk.y - Zn.y;  // Zk + conj(Zn)
            float dx = Zk.x - Zn.x, dy = Zk.y + Zn.y;  // Zk - conj(Zn)
            float tx = dx * wk.x - dy * wk.y;
            float ty = dx * wk.y + dy * wk.x;          // tt = wk * d
            float Xr = 0.5f * (sx + ty);
            float Xi = 0.5f * (sy - tx);
            float P = (Xr * Xr + Xi * Xi) * (1.0f / 8192.0f);
            if ((unsigned)(k - 273) <= 1433u) band += P;     // k in [273,1706]
            int d1 = k - (r - 1);
            if ((unsigned)d1 < 3u) zf[d1] = P;               // r-1, r, r+1
            int d2 = k - (r2 - 1);
            if ((unsigned)d2 < 3u) zf[3 + d2] = P;           // 2r-1, 2r, 2r+1
            wk = cmul(wk, wstep);
        }
    }

    // ---- block reduce band ----
#pragma unroll
    for (int off = 32; off > 0; off >>= 1) band += __shfl_down(band, off);
    if ((t & 63) == 0) zf[8 + (t >> 6)] = band;
    __syncthreads();

    if (t == 0) {
        float bb = zf[8] + zf[9] + zf[10] + zf[11];
        float S = zf[1] + zf[4] + 0.5f * (zf[0] + zf[2]);
        float noise = bb;
        if (r <= 1706)      noise -= zf[1];
        if (r - 1 >= 273)   noise -= 0.5f * zf[0];
        if (r + 1 <= 1706)  noise -= 0.5f * zf[2];
        if (r2 - 1 <= 1706) noise -= zf[3];
        if (r2 <= 1706)     noise -= zf[4];
        if (r2 + 1 <= 1706) noise -= zf[5];
        float loss = -10.0f * log10f(S / (noise + 1.0f));
        atomicAdd(out, loss * (1.0f / 4096.0f));
    }
}

extern "C" void kernel_launch(void* const* d_in, const int* in_sizes, int n_in,
                              void* d_out, int out_size, void* d_ws, size_t ws_size,
                              hipStream_t stream) {
    const float* x = (const float*)d_in[0];    // outputs: (4096, 8192) fp32
    const float* tg = (const float*)d_in[1];   // targets: (4096, 1) fp32
    float* out = (float*)d_out;                // scalar fp32
    hipMemsetAsync(out, 0, sizeof(float), stream);
    snr_kernel<<<4096, TPB, 0, stream>>>(x, tg, out);
}

// Round 4
// 238.434 us; speedup vs baseline: 1.3261x; 1.3261x over previous
//
#include <hip/hip_runtime.h>
#include <math.h>

#define TPB 256

__device__ __forceinline__ float2 cmul(float2 a, float2 b) {
    return make_float2(a.x * b.x - a.y * b.y, a.x * b.y + a.y * b.x);
}

// XOR swizzle on the complex (float2) index: each wave64 b64 access in this
// kernel hits each bank-pair exactly 4x = the 4-round minimum for 512 B.
__device__ __forceinline__ int sw2(int i) { return i ^ ((i >> 4) & 15); }

__device__ __forceinline__ void dft4(float2& a, float2& b, float2& c, float2& d) {
    float2 t0 = make_float2(a.x + c.x, a.y + c.y);
    float2 t1 = make_float2(a.x - c.x, a.y - c.y);
    float2 t2 = make_float2(b.x + d.x, b.y + d.y);
    float2 t3 = make_float2(b.x - d.x, b.y - d.y);
    a = make_float2(t0.x + t2.x, t0.y + t2.y);
    b = make_float2(t1.x + t3.y, t1.y - t3.x);   // t1 - i*t3
    c = make_float2(t0.x - t2.x, t0.y - t2.y);
    d = make_float2(t1.x - t3.y, t1.y + t3.x);   // t1 + i*t3
}

// In-register 16-point DFT. Input v[l]; output y[m] lands at v[4*(m&3) + (m>>2)].
__device__ __forceinline__ void dft16(float2 v[16]) {
#pragma unroll
    for (int j = 0; j < 4; ++j) dft4(v[j], v[4 + j], v[8 + j], v[12 + j]);
    const float C1 = 0.9238795325112867f, S1 = 0.3826834323650898f;
    const float R2 = 0.7071067811865476f;
    v[5]  = cmul(v[5],  make_float2( C1, -S1));   // w16^1
    v[9]  = cmul(v[9],  make_float2( R2, -R2));   // w16^2
    v[13] = cmul(v[13], make_float2( S1, -C1));   // w16^3
    v[6]  = cmul(v[6],  make_float2( R2, -R2));   // w16^2
    v[10] = cmul(v[10], make_float2(0.f, -1.f));  // w16^4
    v[14] = cmul(v[14], make_float2(-R2, -R2));   // w16^6
    v[7]  = cmul(v[7],  make_float2( S1, -C1));   // w16^3
    v[11] = cmul(v[11], make_float2(-R2, -R2));   // w16^6
    v[15] = cmul(v[15], make_float2(-C1,  S1));   // w16^9
#pragma unroll
    for (int b = 0; b < 4; ++b) dft4(v[4 * b], v[4 * b + 1], v[4 * b + 2], v[4 * b + 3]);
}

__global__ __launch_bounds__(TPB, 5) void snr_kernel(const float* __restrict__ x,
                                                     const float* __restrict__ targets,
                                                     float* __restrict__ out) {
    __shared__ __align__(16) float2 Z[4096];   // exactly 32768 B -> 5 blocks/CU
    float* zf = (float*)Z;                     // overlay AFTER final Z reads: spec [0..5], red [8..11]

    const int t = threadIdx.x;
    const int blk = blockIdx.x;

    // ---- every thread computes r (uniform; no LDS broadcast needed) ----
    int r;
    {
        float tg = targets[blk];
        const float df = 0.00244140625f;  // 10/4096 exact; f[i] = i*df exact in fp32
        int c0 = (int)(tg * 409.6f) - 2;
        if (c0 < 0) c0 = 0;
        r = c0;
        float best = fabsf(df * (float)c0 - tg);
        for (int i = c0 + 1; i <= c0 + 4 && i <= 4096; ++i) {
            float dd = fabsf(df * (float)i - tg);
            if (dd < best) { best = dd; r = i; }  // strict <: first-min wins == argmin
        }
    }

    // ---- Load: thread t owns c[t + 256*l] (8B/lane, contiguous per wave) ----
    float2 v[16];
    const float2* row = (const float2*)(x + (size_t)blk * 8192);
#pragma unroll
    for (int l = 0; l < 16; ++l) v[l] = row[t + 256 * l];

    // ======== stage 0: s=1, n=4096, p=t; writes idx=16t+m ========
    dft16(v);
    {
        float ang = -1.5339807878856412e-3f * (float)t;  // -2pi/4096 * t
        float sn, cs; __sincosf(ang, &sn, &cs);
        float2 w1 = make_float2(cs, sn);
        float2 w2 = cmul(w1, w1), w3 = cmul(w2, w1);
        float2 w4 = cmul(w2, w2), w8 = cmul(w4, w4), w12 = cmul(w8, w4);
        float2 wa[4] = {make_float2(1.f, 0.f), w1, w2, w3};
        float2 wb[4] = {make_float2(1.f, 0.f), w4, w8, w12};
#pragma unroll
        for (int m = 0; m < 16; ++m) {
            Z[sw2(16 * t + m)] = cmul(v[4 * (m & 3) + (m >> 2)], cmul(wb[m >> 2], wa[m & 3]));
        }
    }
    __syncthreads();

    // ======== stage 1: s=16, n=256, p=t>>4, q=t&15 ========
#pragma unroll
    for (int l = 0; l < 16; ++l) v[l] = Z[sw2(t + 256 * l)];
    __syncthreads();   // in-place exchange: all reads before any writes
    dft16(v);
    {
        const int p = t >> 4, q = t & 15;
        float ang = -0.02454369260617026f * (float)p;  // -2pi/256 * p
        float sn, cs; __sincosf(ang, &sn, &cs);
        float2 w1 = make_float2(cs, sn);
        float2 w2 = cmul(w1, w1), w3 = cmul(w2, w1);
        float2 w4 = cmul(w2, w2), w8 = cmul(w4, w4), w12 = cmul(w8, w4);
        float2 wa[4] = {make_float2(1.f, 0.f), w1, w2, w3};
        float2 wb[4] = {make_float2(1.f, 0.f), w4, w8, w12};
#pragma unroll
        for (int m = 0; m < 16; ++m) {
            Z[sw2(q + 256 * p + 16 * m)] = cmul(v[4 * (m & 3) + (m >> 2)], cmul(wb[m >> 2], wa[m & 3]));
        }
    }
    __syncthreads();

    // ======== stage 2: s=256, p=0 (no twiddle); Z[t+256m] natural order ========
#pragma unroll
    for (int l = 0; l < 16; ++l) v[l] = Z[sw2(t + 256 * l)];
    __syncthreads();
    dft16(v);
#pragma unroll
    for (int m = 0; m < 16; ++m) {
        Z[sw2(t + 256 * m)] = v[4 * (m & 3) + (m >> 2)];
    }
    __syncthreads();

    // ======== rfft split + band sum; special bins captured in REGISTERS ========
    const int r2 = 2 * r;
    float band = 0.f;
    float p1cap = 0.f, p2cap = 0.f;
    int d1cap = -1, d2cap = -1;
    {
        float ang = -7.669903939428206e-4f * (float)t;  // -pi/4096 * t
        float sn, cs; __sincosf(ang, &sn, &cs);
        float2 wk = make_float2(cs, sn);
        const float2 wstep = make_float2(0.9807852804032304f, -0.19509032201612825f);  // e^{-i pi/16}
#pragma unroll
        for (int m = 0; m < 16; ++m) {
            int k = t + 256 * m;
            float2 Zk = Z[sw2(k)];
            float2 Zn = Z[sw2((4096 - k) & 4095)];
            float sx = Zk.x + Zn.x, sy = Zk.y - Zn.y;  // Zk + conj(Zn)
            float dx = Zk.x - Zn.x, dy = Zk.y + Zn.y;  // Zk - conj(Zn)
            float tx = dx * wk.x - dy * wk.y;
            float ty = dx * wk.y + dy * wk.x;          // tt = wk * d
            float Xr = 0.5f * (sx + ty);
            float Xi = 0.5f * (sy - tx);
            float P = (Xr * Xr + Xi * Xi) * (1.0f / 8192.0f);
            if ((unsigned)(k - 273) <= 1433u) band += P;     // k in [273,1706]
            int d1 = k - (r - 1);
            if ((unsigned)d1 < 3u) { d1cap = d1; p1cap = P; }   // r-1, r, r+1
            int d2 = k - (r2 - 1);
            if ((unsigned)d2 < 3u) { d2cap = d2; p2cap = P; }   // 2r-1, 2r, 2r+1
            wk = cmul(wk, wstep);
        }
    }
    __syncthreads();   // all Z reads done -> overlay zf is safe

    if (d1cap >= 0) zf[d1cap] = p1cap;
    if (d2cap >= 0) zf[3 + d2cap] = p2cap;

    // ---- block reduce band ----
#pragma unroll
    for (int off = 32; off > 0; off >>= 1) band += __shfl_down(band, off);
    if ((t & 63) == 0) zf[8 + (t >> 6)] = band;
    __syncthreads();

    if (t == 0) {
        float bb = zf[8] + zf[9] + zf[10] + zf[11];
        float S = zf[1] + zf[4] + 0.5f * (zf[0] + zf[2]);
        float noise = bb;
        if (r <= 1706)      noise -= zf[1];
        if (r - 1 >= 273)   noise -= 0.5f * zf[0];
        if (r + 1 <= 1706)  noise -= 0.5f * zf[2];
        if (r2 - 1 <= 1706) noise -= zf[3];
        if (r2 <= 1706)     noise -= zf[4];
        if (r2 + 1 <= 1706) noise -= zf[5];
        float loss = -10.0f * log10f(S / (noise + 1.0f));
        atomicAdd(out, loss * (1.0f / 4096.0f));
    }
}

extern "C" void kernel_launch(void* const* d_in, const int* in_sizes, int n_in,
                              void* d_out, int out_size, void* d_ws, size_t ws_size,
                              hipStream_t stream) {
    const float* x = (const float*)d_in[0];    // outputs: (4096, 8192) fp32
    const float* tg = (const float*)d_in[1];   // targets: (4096, 1) fp32
    float* out = (float*)d_out;                // scalar fp32
    hipMemsetAsync(out, 0, sizeof(float), stream);
    snr_kernel<<<4096, TPB, 0, stream>>>(x, tg, out);
}

// Round 5
// 219.401 us; speedup vs baseline: 1.4412x; 1.0868x over previous
//
#include <hip/hip_runtime.h>
#include <math.h>

#define TPB 256

__device__ __forceinline__ float2 cmul(float2 a, float2 b) {
    return make_float2(a.x * b.x - a.y * b.y, a.x * b.y + a.y * b.x);
}

// XOR swizzle on the complex (float2) index: each wave64 b64 access in this
// kernel hits each bank-pair exactly 4x = the 4-round minimum for 512 B.
__device__ __forceinline__ int sw2(int i) { return i ^ ((i >> 4) & 15); }

__device__ __forceinline__ void dft4(float2& a, float2& b, float2& c, float2& d) {
    float2 t0 = make_float2(a.x + c.x, a.y + c.y);
    float2 t1 = make_float2(a.x - c.x, a.y - c.y);
    float2 t2 = make_float2(b.x + d.x, b.y + d.y);
    float2 t3 = make_float2(b.x - d.x, b.y - d.y);
    a = make_float2(t0.x + t2.x, t0.y + t2.y);
    b = make_float2(t1.x + t3.y, t1.y - t3.x);   // t1 - i*t3
    c = make_float2(t0.x - t2.x, t0.y - t2.y);
    d = make_float2(t1.x - t3.y, t1.y + t3.x);   // t1 + i*t3
}

// In-register 16-point DFT. Input v[l]; output y[m] lands at v[4*(m&3) + (m>>2)].
__device__ __forceinline__ void dft16(float2 v[16]) {
#pragma unroll
    for (int j = 0; j < 4; ++j) dft4(v[j], v[4 + j], v[8 + j], v[12 + j]);
    const float C1 = 0.9238795325112867f, S1 = 0.3826834323650898f;
    const float R2 = 0.7071067811865476f;
    v[5]  = cmul(v[5],  make_float2( C1, -S1));   // w16^1
    v[9]  = cmul(v[9],  make_float2( R2, -R2));   // w16^2
    v[13] = cmul(v[13], make_float2( S1, -C1));   // w16^3
    v[6]  = cmul(v[6],  make_float2( R2, -R2));   // w16^2
    v[10] = cmul(v[10], make_float2(0.f, -1.f));  // w16^4
    v[14] = cmul(v[14], make_float2(-R2, -R2));   // w16^6
    v[7]  = cmul(v[7],  make_float2( S1, -C1));   // w16^3
    v[11] = cmul(v[11], make_float2(-R2, -R2));   // w16^6
    v[15] = cmul(v[15], make_float2(-C1,  S1));   // w16^9
#pragma unroll
    for (int b = 0; b < 4; ++b) dft4(v[4 * b], v[4 * b + 1], v[4 * b + 2], v[4 * b + 3]);
}

// NOTE: min_waves=4, NOT 5 — declaring 5 drove the backend to a 48-VGPR
// allocation and ~104 B/thread scratch spill (R3/R4: WRITE_SIZE 106-330 MB).
// With LDS = 32768 B exactly, HW can still co-resident 5 blocks/CU.
__global__ __launch_bounds__(TPB, 4) void snr_kernel(const float* __restrict__ x,
                                                     const float* __restrict__ targets,
                                                     float* __restrict__ out) {
    __shared__ __align__(16) float2 Z[4096];   // exactly 32768 B
    float* zf = (float*)Z;                     // overlay AFTER final Z reads: spec [0..5], red [8..11]

    const int t = threadIdx.x;
    const int blk = blockIdx.x;

    // ---- every thread computes r (uniform; no LDS broadcast needed) ----
    int r;
    {
        float tg = targets[blk];
        const float df = 0.00244140625f;  // 10/4096 exact; f[i] = i*df exact in fp32
        int c0 = (int)(tg * 409.6f) - 2;
        if (c0 < 0) c0 = 0;
        r = c0;
        float best = fabsf(df * (float)c0 - tg);
        for (int i = c0 + 1; i <= c0 + 4 && i <= 4096; ++i) {
            float dd = fabsf(df * (float)i - tg);
            if (dd < best) { best = dd; r = i; }  // strict <: first-min wins == argmin
        }
    }

    // ---- Load: thread t owns c[t + 256*l] (8B/lane, contiguous per wave) ----
    float2 v[16];
    const float2* row = (const float2*)(x + (size_t)blk * 8192);
#pragma unroll
    for (int l = 0; l < 16; ++l) v[l] = row[t + 256 * l];

    // ======== stage 0: s=1, n=4096, p=t; writes idx=16t+m ========
    dft16(v);
    {
        float ang = -1.5339807878856412e-3f * (float)t;  // -2pi/4096 * t
        float sn, cs; __sincosf(ang, &sn, &cs);
        float2 w1 = make_float2(cs, sn);
        float2 w2 = cmul(w1, w1), w3 = cmul(w2, w1);
        float2 w4 = cmul(w2, w2), w8 = cmul(w4, w4), w12 = cmul(w8, w4);
        float2 wa[4] = {make_float2(1.f, 0.f), w1, w2, w3};
        float2 wb[4] = {make_float2(1.f, 0.f), w4, w8, w12};
#pragma unroll
        for (int m = 0; m < 16; ++m) {
            Z[sw2(16 * t + m)] = cmul(v[4 * (m & 3) + (m >> 2)], cmul(wb[m >> 2], wa[m & 3]));
        }
    }
    __syncthreads();

    // ======== stage 1: s=16, n=256, p=t>>4, q=t&15 ========
#pragma unroll
    for (int l = 0; l < 16; ++l) v[l] = Z[sw2(t + 256 * l)];
    __syncthreads();   // in-place exchange: all reads before any writes
    dft16(v);
    {
        const int p = t >> 4, q = t & 15;
        float ang = -0.02454369260617026f * (float)p;  // -2pi/256 * p
        float sn, cs; __sincosf(ang, &sn, &cs);
        float2 w1 = make_float2(cs, sn);
        float2 w2 = cmul(w1, w1), w3 = cmul(w2, w1);
        float2 w4 = cmul(w2, w2), w8 = cmul(w4, w4), w12 = cmul(w8, w4);
        float2 wa[4] = {make_float2(1.f, 0.f), w1, w2, w3};
        float2 wb[4] = {make_float2(1.f, 0.f), w4, w8, w12};
#pragma unroll
        for (int m = 0; m < 16; ++m) {
            Z[sw2(q + 256 * p + 16 * m)] = cmul(v[4 * (m & 3) + (m >> 2)], cmul(wb[m >> 2], wa[m & 3]));
        }
    }
    __syncthreads();

    // ======== stage 2: s=256, p=0 (no twiddle); Z[t+256m] natural order ========
#pragma unroll
    for (int l = 0; l < 16; ++l) v[l] = Z[sw2(t + 256 * l)];
    __syncthreads();
    dft16(v);
#pragma unroll
    for (int m = 0; m < 16; ++m) {
        Z[sw2(t + 256 * m)] = v[4 * (m & 3) + (m >> 2)];
    }
    __syncthreads();

    // ======== rfft split + band sum ========
    // Zk for k = t+256m is ALREADY in registers (v) — only Zn comes from LDS.
    const int r2 = 2 * r;
    float band = 0.f;
    float p1cap = 0.f, p2cap = 0.f;
    int d1cap = -1, d2cap = -1;
    {
        float ang = -7.669903939428206e-4f * (float)t;  // -pi/4096 * t
        float sn, cs; __sincosf(ang, &sn, &cs);
        float2 wk = make_float2(cs, sn);
        const float2 wstep = make_float2(0.9807852804032304f, -0.19509032201612825f);  // e^{-i pi/16}
#pragma unroll
        for (int m = 0; m < 16; ++m) {
            int k = t + 256 * m;
            float2 Zk = v[4 * (m & 3) + (m >> 2)];
            float2 Zn = Z[sw2((4096 - k) & 4095)];
            float sx = Zk.x + Zn.x, sy = Zk.y - Zn.y;  // Zk + conj(Zn)
            float dx = Zk.x - Zn.x, dy = Zk.y + Zn.y;  // Zk - conj(Zn)
            float tx = dx * wk.x - dy * wk.y;
            float ty = dx * wk.y + dy * wk.x;          // tt = wk * d
            float Xr = 0.5f * (sx + ty);
            float Xi = 0.5f * (sy - tx);
            float P = (Xr * Xr + Xi * Xi) * (1.0f / 8192.0f);
            if ((unsigned)(k - 273) <= 1433u) band += P;     // k in [273,1706]
            int d1 = k - (r - 1);
            if ((unsigned)d1 < 3u) { d1cap = d1; p1cap = P; }   // r-1, r, r+1
            int d2 = k - (r2 - 1);
            if ((unsigned)d2 < 3u) { d2cap = d2; p2cap = P; }   // 2r-1, 2r, 2r+1
            wk = cmul(wk, wstep);
        }
    }
    __syncthreads();   // all Z reads done -> overlay zf is safe

    if (d1cap >= 0) zf[d1cap] = p1cap;
    if (d2cap >= 0) zf[3 + d2cap] = p2cap;

    // ---- block reduce band ----
#pragma unroll
    for (int off = 32; off > 0; off >>= 1) band += __shfl_down(band, off);
    if ((t & 63) == 0) zf[8 + (t >> 6)] = band;
    __syncthreads();

    if (t == 0) {
        float bb = zf[8] + zf[9] + zf[10] + zf[11];
        float S = zf[1] + zf[4] + 0.5f * (zf[0] + zf[2]);
        float noise = bb;
        if (r <= 1706)      noise -= zf[1];
        if (r - 1 >= 273)   noise -= 0.5f * zf[0];
        if (r + 1 <= 1706)  noise -= 0.5f * zf[2];
        if (r2 - 1 <= 1706) noise -= zf[3];
        if (r2 <= 1706)     noise -= zf[4];
        if (r2 + 1 <= 1706) noise -= zf[5];
        float loss = -10.0f * log10f(S / (noise + 1.0f));
        atomicAdd(out, loss * (1.0f / 4096.0f));
    }
}

extern "C" void kernel_launch(void* const* d_in, const int* in_sizes, int n_in,
                              void* d_out, int out_size, void* d_ws, size_t ws_size,
                              hipStream_t stream) {
    const float* x = (const float*)d_in[0];    // outputs: (4096, 8192) fp32
    const float* tg = (const float*)d_in[1];   // targets: (4096, 1) fp32
    float* out = (float*)d_out;                // scalar fp32
    hipMemsetAsync(out, 0, sizeof(float), stream);
    snr_kernel<<<4096, TPB, 0, stream>>>(x, tg, out);
}

// Round 6
// 212.029 us; speedup vs baseline: 1.4913x; 1.0348x over previous
//
#include <hip/hip_runtime.h>
#include <math.h>

#define TPB 256

// Packed complex: clang ext_vector_type(2) float -> VOP3P v_pk_{add,mul,fma}_f32
// on gfx950 (2x fp32 per instruction vs scalar VALU).
typedef float cplx __attribute__((ext_vector_type(2)));

__device__ __forceinline__ cplx cmul(cplx a, cplx b) {
    // (a.x*b.x - a.y*b.y, a.x*b.y + a.y*b.x) = a.xx*b + (-a.y, a.y)*b.yx
    return a.xx * b + cplx{-a.y, a.y} * b.yx;
}

// XOR swizzle on the complex (float2) index: each wave64 b64 access in this
// kernel hits each bank-pair exactly 4x = the 4-round minimum for 512 B.
__device__ __forceinline__ int sw2(int i) { return i ^ ((i >> 4) & 15); }

__device__ __forceinline__ void dft4(cplx& a, cplx& b, cplx& c, cplx& d) {
    cplx t0 = a + c, t1 = a - c, t2 = b + d, t3 = b - d;
    a = t0 + t2;
    c = t0 - t2;
    cplx jt3 = cplx{t3.y, -t3.x};   // -i * t3
    b = t1 + jt3;
    d = t1 - jt3;
}

// In-register 16-point DFT. Input v[l]; output y[m] lands at v[4*(m&3) + (m>>2)].
__device__ __forceinline__ void dft16(cplx v[16]) {
#pragma unroll
    for (int j = 0; j < 4; ++j) dft4(v[j], v[4 + j], v[8 + j], v[12 + j]);
    const float C1 = 0.9238795325112867f, S1 = 0.3826834323650898f;
    const float R2 = 0.7071067811865476f;
    v[5]  = cmul(v[5],  cplx{ C1, -S1});   // w16^1
    v[9]  = cmul(v[9],  cplx{ R2, -R2});   // w16^2
    v[13] = cmul(v[13], cplx{ S1, -C1});   // w16^3
    v[6]  = cmul(v[6],  cplx{ R2, -R2});   // w16^2
    v[10] = cplx{v[10].y, -v[10].x};       // * w16^4 = -i
    v[14] = cmul(v[14], cplx{-R2, -R2});   // w16^6
    v[7]  = cmul(v[7],  cplx{ S1, -C1});   // w16^3
    v[11] = cmul(v[11], cplx{-R2, -R2});   // w16^6
    v[15] = cmul(v[15], cplx{-C1,  S1});   // w16^9
#pragma unroll
    for (int b = 0; b < 4; ++b) dft4(v[4 * b], v[4 * b + 1], v[4 * b + 2], v[4 * b + 3]);
}

// min_waves=4, NOT 5 — declaring 5 drove the backend to a 48-VGPR allocation
// and ~104 B/thread scratch spill (R3/R4: WRITE_SIZE 106-330 MB). With LDS =
// 32768 B exactly, HW can still co-resident 5 blocks/CU when VGPRs permit.
__global__ __launch_bounds__(TPB, 4) void snr_kernel(const float* __restrict__ x,
                                                     const float* __restrict__ targets,
                                                     float* __restrict__ out) {
    __shared__ __align__(16) cplx Z[4096];   // exactly 32768 B
    float* zf = (float*)Z;                   // overlay AFTER final Z reads: spec [0..5], red [8..11]

    const int t = threadIdx.x;
    const int blk = blockIdx.x;

    // ---- every thread computes r (uniform; no LDS broadcast needed) ----
    int r;
    {
        float tg = targets[blk];
        const float df = 0.00244140625f;  // 10/4096 exact; f[i] = i*df exact in fp32
        int c0 = (int)(tg * 409.6f) - 2;
        if (c0 < 0) c0 = 0;
        r = c0;
        float best = fabsf(df * (float)c0 - tg);
        for (int i = c0 + 1; i <= c0 + 4 && i <= 4096; ++i) {
            float dd = fabsf(df * (float)i - tg);
            if (dd < best) { best = dd; r = i; }  // strict <: first-min wins == argmin
        }
    }

    // ---- Load: thread t owns c[t + 256*l] (8B/lane, contiguous per wave) ----
    cplx v[16];
    const cplx* row = (const cplx*)(x + (size_t)blk * 8192);
#pragma unroll
    for (int l = 0; l < 16; ++l) v[l] = row[t + 256 * l];

    // ======== stage 0: s=1, n=4096, p=t; writes idx=16t+m ========
    dft16(v);
    {
        float ang = -1.5339807878856412e-3f * (float)t;  // -2pi/4096 * t
        float sn, cs; __sincosf(ang, &sn, &cs);
        cplx w1 = cplx{cs, sn};
        cplx w2 = cmul(w1, w1), w3 = cmul(w2, w1);
        cplx w4 = cmul(w2, w2), w8 = cmul(w4, w4), w12 = cmul(w8, w4);
        cplx wa[4] = {cplx{1.f, 0.f}, w1, w2, w3};
        cplx wb[4] = {cplx{1.f, 0.f}, w4, w8, w12};
#pragma unroll
        for (int m = 0; m < 16; ++m) {
            Z[sw2(16 * t + m)] = cmul(v[4 * (m & 3) + (m >> 2)], cmul(wb[m >> 2], wa[m & 3]));
        }
    }
    __syncthreads();

    // ======== stage 1: s=16, n=256, p=t>>4, q=t&15 ========
#pragma unroll
    for (int l = 0; l < 16; ++l) v[l] = Z[sw2(t + 256 * l)];
    __syncthreads();   // in-place exchange: all reads before any writes
    dft16(v);
    {
        const int p = t >> 4, q = t & 15;
        float ang = -0.02454369260617026f * (float)p;  // -2pi/256 * p
        float sn, cs; __sincosf(ang, &sn, &cs);
        cplx w1 = cplx{cs, sn};
        cplx w2 = cmul(w1, w1), w3 = cmul(w2, w1);
        cplx w4 = cmul(w2, w2), w8 = cmul(w4, w4), w12 = cmul(w8, w4);
        cplx wa[4] = {cplx{1.f, 0.f}, w1, w2, w3};
        cplx wb[4] = {cplx{1.f, 0.f}, w4, w8, w12};
#pragma unroll
        for (int m = 0; m < 16; ++m) {
            Z[sw2(q + 256 * p + 16 * m)] = cmul(v[4 * (m & 3) + (m >> 2)], cmul(wb[m >> 2], wa[m & 3]));
        }
    }
    __syncthreads();

    // ======== stage 2: s=256, p=0 (no twiddle); Z[t+256m] natural order ========
#pragma unroll
    for (int l = 0; l < 16; ++l) v[l] = Z[sw2(t + 256 * l)];
    __syncthreads();
    dft16(v);
#pragma unroll
    for (int m = 0; m < 16; ++m) {
        Z[sw2(t + 256 * m)] = v[4 * (m & 3) + (m >> 2)];
    }
    __syncthreads();

    // ======== rfft split + band sum ========
    // Zk for k = t+256m is ALREADY in registers (v) — only Zn comes from LDS.
    const int r2 = 2 * r;
    float band = 0.f;
    float p1cap = 0.f, p2cap = 0.f;
    int d1cap = -1, d2cap = -1;
    {
        float ang = -7.669903939428206e-4f * (float)t;  // -pi/4096 * t
        float sn, cs; __sincosf(ang, &sn, &cs);
        cplx wk = cplx{cs, sn};
        const cplx wstep = cplx{0.9807852804032304f, -0.19509032201612825f};  // e^{-i pi/16}
#pragma unroll
        for (int m = 0; m < 16; ++m) {
            int k = t + 256 * m;
            cplx Zk = v[4 * (m & 3) + (m >> 2)];
            cplx Zn = Z[sw2((4096 - k) & 4095)];
            cplx Znc = cplx{Zn.x, -Zn.y};          // conj(Zn)
            cplx s  = Zk + Znc;
            cplx dd = Zk - Znc;
            cplx tt = cmul(wk, dd);
            cplx X  = 0.5f * (s + cplx{tt.y, -tt.x});
            float P = (X.x * X.x + X.y * X.y) * (1.0f / 8192.0f);
            if ((unsigned)(k - 273) <= 1433u) band += P;     // k in [273,1706]
            int d1 = k - (r - 1);
            if ((unsigned)d1 < 3u) { d1cap = d1; p1cap = P; }   // r-1, r, r+1
            int d2 = k - (r2 - 1);
            if ((unsigned)d2 < 3u) { d2cap = d2; p2cap = P; }   // 2r-1, 2r, 2r+1
            wk = cmul(wk, wstep);
        }
    }
    __syncthreads();   // all Z reads done -> overlay zf is safe

    if (d1cap >= 0) zf[d1cap] = p1cap;
    if (d2cap >= 0) zf[3 + d2cap] = p2cap;

    // ---- block reduce band ----
#pragma unroll
    for (int off = 32; off > 0; off >>= 1) band += __shfl_down(band, off);
    if ((t & 63) == 0) zf[8 + (t >> 6)] = band;
    __syncthreads();

    if (t == 0) {
        float bb = zf[8] + zf[9] + zf[10] + zf[11];
        float S = zf[1] + zf[4] + 0.5f * (zf[0] + zf[2]);
        float noise = bb;
        if (r <= 1706)      noise -= zf[1];
        if (r - 1 >= 273)   noise -= 0.5f * zf[0];
        if (r + 1 <= 1706)  noise -= 0.5f * zf[2];
        if (r2 - 1 <= 1706) noise -= zf[3];
        if (r2 <= 1706)     noise -= zf[4];
        if (r2 + 1 <= 1706) noise -= zf[5];
        float loss = -10.0f * log10f(S / (noise + 1.0f));
        atomicAdd(out, loss * (1.0f / 4096.0f));
    }
}

extern "C" void kernel_launch(void* const* d_in, const int* in_sizes, int n_in,
                              void* d_out, int out_size, void* d_ws, size_t ws_size,
                              hipStream_t stream) {
    const float* x = (const float*)d_in[0];    // outputs: (4096, 8192) fp32
    const float* tg = (const float*)d_in[1];   // targets: (4096, 1) fp32
    float* out = (float*)d_out;                // scalar fp32
    hipMemsetAsync(out, 0, sizeof(float), stream);
    snr_kernel<<<4096, TPB, 0, stream>>>(x, tg, out);
}